// Round 1
// baseline (1113.376 us; speedup 1.0000x reference)
//
#include <hip/hip_runtime.h>

// MaskAttention: B=4, C=128, H=W=64 -> N=4096
// Round 1: correct fp32 baseline.
//   k1: QKV projections -> ws as (B,N,C) fp32
//   k2: flash attention (TQ=64, TK=32) + residual + LayerNorm + transposed store
// ws layout (floats): Q[0 .. 2M), K[2M .. 4M), V[4M .. 6M)   (M = B*N*C = 2^21)

#define CCH 128
#define NTOK 4096

__global__ __launch_bounds__(256) void qkv_kernel(
    const float* __restrict__ prompt, const float* __restrict__ xg,
    const float* __restrict__ Wq, const float* __restrict__ bq,
    const float* __restrict__ Wk, const float* __restrict__ bk,
    const float* __restrict__ Wv, const float* __restrict__ bv,
    float* __restrict__ Qo, float* __restrict__ Ko, float* __restrict__ Vo)
{
    // tiles: [c][n] 128 x 64, no pad (compute reads are wave-broadcast)
    __shared__ float ps[128 * 64];
    __shared__ float xs[128 * 64];
    const int t  = threadIdx.x;
    const int b  = blockIdx.x >> 6;
    const int n0 = (blockIdx.x & 63) << 6;

    {   // stage tiles: thread t -> row c = t>>1, half nh = (t&1)*32
        const int c = t >> 1, nh = (t & 1) << 5;
        const float* srcp = prompt + (((size_t)b * CCH + c) << 12) + n0 + nh;
        const float* srcx = xg     + (((size_t)b * CCH + c) << 12) + n0 + nh;
        float* dp = ps + c * 64 + nh;
        float* dx = xs + c * 64 + nh;
        #pragma unroll
        for (int k = 0; k < 32; k += 4) {
            *reinterpret_cast<float4*>(dp + k) = *reinterpret_cast<const float4*>(srcp + k);
            *reinterpret_cast<float4*>(dx + k) = *reinterpret_cast<const float4*>(srcx + k);
        }
    }
    __syncthreads();

    const int co   = t & 127;       // output channel
    const int half = t >> 7;        // token half (0/1)
    const float4* wq4 = reinterpret_cast<const float4*>(Wq + co * CCH);
    const float4* wk4 = reinterpret_cast<const float4*>(Wk + co * CCH);
    const float4* wv4 = reinterpret_cast<const float4*>(Wv + co * CCH);
    const float bqv = bq[co], bkv = bk[co], bvv = bv[co];

    for (int nb = 0; nb < 32; nb += 8) {
        const int n = (half << 5) + nb;
        float aq[8] = {0,0,0,0,0,0,0,0};
        float ak[8] = {0,0,0,0,0,0,0,0};
        float av[8] = {0,0,0,0,0,0,0,0};
        for (int c4 = 0; c4 < 32; ++c4) {
            const float4 wqv = wq4[c4], wkv = wk4[c4], wvv = wv4[c4];
            #pragma unroll
            for (int cc = 0; cc < 4; ++cc) {
                const float wqc = (cc==0)?wqv.x:(cc==1)?wqv.y:(cc==2)?wqv.z:wqv.w;
                const float wkc = (cc==0)?wkv.x:(cc==1)?wkv.y:(cc==2)?wkv.z:wkv.w;
                const float wvc = (cc==0)?wvv.x:(cc==1)?wvv.y:(cc==2)?wvv.z:wvv.w;
                const float* pr = ps + (c4 * 4 + cc) * 64 + n;
                const float* xr = xs + (c4 * 4 + cc) * 64 + n;
                float pa[8], xa[8];
                *reinterpret_cast<float4*>(&pa[0]) = *reinterpret_cast<const float4*>(pr);
                *reinterpret_cast<float4*>(&pa[4]) = *reinterpret_cast<const float4*>(pr + 4);
                *reinterpret_cast<float4*>(&xa[0]) = *reinterpret_cast<const float4*>(xr);
                *reinterpret_cast<float4*>(&xa[4]) = *reinterpret_cast<const float4*>(xr + 4);
                #pragma unroll
                for (int u = 0; u < 8; ++u) {
                    aq[u] += wqc * pa[u];
                    ak[u] += wkc * xa[u];
                    av[u] += wvc * xa[u];
                }
            }
        }
        const size_t base = ((size_t)(b * NTOK + n0 + n)) * CCH + co;
        #pragma unroll
        for (int u = 0; u < 8; ++u) {
            Qo[base + (size_t)u * CCH] = aq[u] + bqv;
            Ko[base + (size_t)u * CCH] = ak[u] + bkv;
            Vo[base + (size_t)u * CCH] = av[u] + bvv;
        }
    }
}

// Flash attention + residual + LayerNorm + transposed output.
// Block: 256 threads = 16 tc x 16 tr. Thread owns rows 4*tr+i (i<4).
// S phase: cols 2*tc+j (j<2).  PV/epilogue: channels 8*tc+j (j<8).
__global__ __launch_bounds__(256) void attn_ln_kernel(
    const float* __restrict__ Qg, const float* __restrict__ Kg, const float* __restrict__ Vg,
    const int* __restrict__ maskb, const float* __restrict__ xg,
    const float* __restrict__ gamma, const float* __restrict__ beta,
    float* __restrict__ out)
{
    __shared__ float pool[14976];   // Qs 64x132 | KVs 32x132 | Ps 64x36
    __shared__ int   ms[32];
    float* Qs  = pool;              // 8448 floats
    float* KVs = pool + 8448;       // 4224 floats
    float* Ps  = pool + 12672;      // 2304 floats

    const int t  = threadIdx.x;
    const int b  = blockIdx.x >> 6;
    const int n0 = (blockIdx.x & 63) << 6;
    const int tc = t & 15, tr = t >> 4;

    {   // load Q tile 64x128
        const int r = t >> 2, c0 = (t & 3) << 5;
        const float* src = Qg + (((size_t)(b * NTOK + n0 + r)) << 7) + c0;
        float* dst = Qs + r * 132 + c0;
        #pragma unroll
        for (int k = 0; k < 32; k += 4)
            *reinterpret_cast<float4*>(dst + k) = *reinterpret_cast<const float4*>(src + k);
    }

    float mrun[4], lrun[4], acc[4][8];
    #pragma unroll
    for (int i = 0; i < 4; ++i) {
        mrun[i] = -1e30f; lrun[i] = 0.f;
        #pragma unroll
        for (int j = 0; j < 8; ++j) acc[i][j] = 0.f;
    }
    const float scale = 0.08838834764831845f;  // 1/sqrt(128)

    for (int kt = 0; kt < 128; ++kt) {
        const int m0 = kt << 5;
        __syncthreads();                         // prev PV done with KVs/Ps
        {   // load K tile 32x128
            const int r = t >> 3, c0 = (t & 7) << 4;
            const float* src = Kg + (((size_t)(b * NTOK + m0 + r)) << 7) + c0;
            float* dst = KVs + r * 132 + c0;
            #pragma unroll
            for (int k = 0; k < 16; k += 4)
                *reinterpret_cast<float4*>(dst + k) = *reinterpret_cast<const float4*>(src + k);
            if (t < 32) ms[t] = maskb[b * NTOK + m0 + t];
        }
        __syncthreads();

        // S = Q K^T
        float s[4][2] = {{0.f,0.f},{0.f,0.f},{0.f,0.f},{0.f,0.f}};
        #pragma unroll 4
        for (int k = 0; k < 128; k += 4) {
            const float4 kv0 = *reinterpret_cast<const float4*>(KVs + (2*tc    ) * 132 + k);
            const float4 kv1 = *reinterpret_cast<const float4*>(KVs + (2*tc + 1) * 132 + k);
            #pragma unroll
            for (int i = 0; i < 4; ++i) {
                const float4 qv = *reinterpret_cast<const float4*>(Qs + (4*tr + i) * 132 + k);
                s[i][0] += qv.x*kv0.x + qv.y*kv0.y + qv.z*kv0.z + qv.w*kv0.w;
                s[i][1] += qv.x*kv1.x + qv.y*kv1.y + qv.z*kv1.z + qv.w*kv1.w;
            }
        }

        const int mk0 = ms[2*tc], mk1 = ms[2*tc + 1];
        #pragma unroll
        for (int i = 0; i < 4; ++i) {
            const float s0 = mk0 ? s[i][0] * scale : -1e30f;
            const float s1 = mk1 ? s[i][1] * scale : -1e30f;
            float rm = fmaxf(s0, s1);
            rm = fmaxf(rm, __shfl_xor(rm, 1));
            rm = fmaxf(rm, __shfl_xor(rm, 2));
            rm = fmaxf(rm, __shfl_xor(rm, 4));
            rm = fmaxf(rm, __shfl_xor(rm, 8));
            const float mn = fmaxf(mrun[i], rm);
            const float cr = __expf(mrun[i] - mn);
            const float p0 = __expf(s0 - mn);
            const float p1 = __expf(s1 - mn);
            float rs = p0 + p1;
            rs += __shfl_xor(rs, 1);
            rs += __shfl_xor(rs, 2);
            rs += __shfl_xor(rs, 4);
            rs += __shfl_xor(rs, 8);
            mrun[i] = mn;
            lrun[i] = lrun[i] * cr + rs;
            #pragma unroll
            for (int j = 0; j < 8; ++j) acc[i][j] *= cr;
            Ps[(4*tr + i) * 36 + 2*tc    ] = p0;
            Ps[(4*tr + i) * 36 + 2*tc + 1] = p1;
        }
        __syncthreads();                         // Ps visible; K reads done
        {   // load V tile 32x128 over KVs
            const int r = t >> 3, c0 = (t & 7) << 4;
            const float* src = Vg + (((size_t)(b * NTOK + m0 + r)) << 7) + c0;
            float* dst = KVs + r * 132 + c0;
            #pragma unroll
            for (int k = 0; k < 16; k += 4)
                *reinterpret_cast<float4*>(dst + k) = *reinterpret_cast<const float4*>(src + k);
        }
        __syncthreads();                         // V visible

        // PV: acc[i][ch] += P[row][m] * V[m][ch]
        #pragma unroll 2
        for (int m = 0; m < 32; m += 4) {
            float pv[4][4];
            #pragma unroll
            for (int i = 0; i < 4; ++i)
                *reinterpret_cast<float4*>(&pv[i][0]) =
                    *reinterpret_cast<const float4*>(Ps + (4*tr + i) * 36 + m);
            #pragma unroll
            for (int mm = 0; mm < 4; ++mm) {
                float va[8];
                *reinterpret_cast<float4*>(&va[0]) =
                    *reinterpret_cast<const float4*>(KVs + (m + mm) * 132 + 8*tc);
                *reinterpret_cast<float4*>(&va[4]) =
                    *reinterpret_cast<const float4*>(KVs + (m + mm) * 132 + 8*tc + 4);
                #pragma unroll
                for (int i = 0; i < 4; ++i) {
                    const float pw = pv[i][mm];
                    #pragma unroll
                    for (int j = 0; j < 8; ++j) acc[i][j] += pw * va[j];
                }
            }
        }
    }

    // ---------------- epilogue: residual + LayerNorm + transpose ----------------
    __syncthreads();
    float* stg = pool;   // reuse: [128][65] = 8320 floats
    {   // stage x tile (c-major) for residual
        const int c = t >> 1, nh = (t & 1) << 5;
        const float* src = xg + (((size_t)b * CCH + c) << 12) + n0 + nh;
        float* dst = stg + c * 65 + nh;
        #pragma unroll
        for (int k = 0; k < 32; k += 4) {
            const float4 v = *reinterpret_cast<const float4*>(src + k);
            dst[k] = v.x; dst[k+1] = v.y; dst[k+2] = v.z; dst[k+3] = v.w;
        }
    }
    __syncthreads();

    float g[8], be[8];
    #pragma unroll
    for (int j = 0; j < 8; ++j) { g[j] = gamma[8*tc + j]; be[j] = beta[8*tc + j]; }

    #pragma unroll
    for (int i = 0; i < 4; ++i) {
        const int n = 4*tr + i;
        const float inv = 1.f / lrun[i];
        float sum = 0.f, sq = 0.f;
        #pragma unroll
        for (int j = 0; j < 8; ++j) {
            const float v = acc[i][j] * inv + stg[(8*tc + j) * 65 + n];
            acc[i][j] = v; sum += v; sq += v * v;
        }
        sum += __shfl_xor(sum, 1); sq += __shfl_xor(sq, 1);
        sum += __shfl_xor(sum, 2); sq += __shfl_xor(sq, 2);
        sum += __shfl_xor(sum, 4); sq += __shfl_xor(sq, 4);
        sum += __shfl_xor(sum, 8); sq += __shfl_xor(sq, 8);
        const float mean = sum * (1.f / 128.f);
        const float var  = sq * (1.f / 128.f) - mean * mean;
        const float rstd = rsqrtf(var + 1e-5f);
        #pragma unroll
        for (int j = 0; j < 8; ++j)
            acc[i][j] = (acc[i][j] - mean) * rstd * g[j] + be[j];
    }
    __syncthreads();    // residual reads of stg done

    #pragma unroll
    for (int i = 0; i < 4; ++i) {
        #pragma unroll
        for (int j = 0; j < 8; ++j)
            stg[(8*tc + j) * 65 + 4*tr + i] = acc[i][j];
    }
    __syncthreads();

    {   // coalesced transposed store
        const int c = t >> 1, nh = (t & 1) << 5;
        float* dst = out + (((size_t)b * CCH + c) << 12) + n0 + nh;
        const float* srcl = stg + c * 65 + nh;
        #pragma unroll
        for (int k = 0; k < 32; k += 4) {
            float4 v; v.x = srcl[k]; v.y = srcl[k+1]; v.z = srcl[k+2]; v.w = srcl[k+3];
            *reinterpret_cast<float4*>(dst + k) = v;
        }
    }
}

extern "C" void kernel_launch(void* const* d_in, const int* in_sizes, int n_in,
                              void* d_out, int out_size, void* d_ws, size_t ws_size,
                              hipStream_t stream) {
    const float* prompt = (const float*)d_in[0];
    const float* x      = (const float*)d_in[1];
    const float* Wq     = (const float*)d_in[2];
    const float* bq     = (const float*)d_in[3];
    const float* Wk     = (const float*)d_in[4];
    const float* bk     = (const float*)d_in[5];
    const float* Wv     = (const float*)d_in[6];
    const float* bv     = (const float*)d_in[7];
    const float* gamma  = (const float*)d_in[8];
    const float* beta   = (const float*)d_in[9];
    const int*   maskb  = (const int*)d_in[10];
    float* out = (float*)d_out;

    const size_t M = (size_t)4 * NTOK * CCH;   // 2,097,152
    float* Qw = (float*)d_ws;
    float* Kw = Qw + M;
    float* Vw = Kw + M;

    qkv_kernel<<<256, 256, 0, stream>>>(prompt, x, Wq, bq, Wk, bk, Wv, bv, Qw, Kw, Vw);
    attn_ln_kernel<<<256, 256, 0, stream>>>(Qw, Kw, Vw, maskb, x, gamma, beta, out);
}

// Round 2
// 270.118 us; speedup vs baseline: 4.1218x; 4.1218x over previous
//
#include <hip/hip_runtime.h>

// MaskAttention: B=4, C=128, H=W=64 -> N=4096
// Round 2: bf16 MFMA flash attention.
//   k1 (fp32 compute): QKV -> ws bf16. Q,K as (B,N,C); V as (B,C,N). Q pre-scaled 1/sqrt(C).
//   k2: MFMA flash attention (TQ=64, TK=64) + residual + LayerNorm + transposed fp32 store.

#define CCH 128
#define NTOK 4096

typedef __attribute__((ext_vector_type(8))) short  bf16x8;
typedef __attribute__((ext_vector_type(8))) unsigned short ushort8;
typedef __attribute__((ext_vector_type(4))) float  f32x4;

__device__ __forceinline__ unsigned short f2bf(float f) {
    unsigned int u = __builtin_bit_cast(unsigned int, f);
    u += 0x7FFFu + ((u >> 16) & 1u);      // RNE (inputs are finite)
    return (unsigned short)(u >> 16);
}

__global__ __launch_bounds__(256) void qkv_kernel(
    const float* __restrict__ prompt, const float* __restrict__ xg,
    const float* __restrict__ Wq, const float* __restrict__ bq,
    const float* __restrict__ Wk, const float* __restrict__ bk,
    const float* __restrict__ Wv, const float* __restrict__ bv,
    unsigned short* __restrict__ Qo, unsigned short* __restrict__ Ko,
    unsigned short* __restrict__ Vo)
{
    __shared__ float ps[128 * 64];
    __shared__ float xs[128 * 64];
    const int t  = threadIdx.x;
    const int b  = blockIdx.x >> 6;
    const int n0 = (blockIdx.x & 63) << 6;

    {   // stage tiles: thread t -> row c = t>>1, half nh = (t&1)*32
        const int c = t >> 1, nh = (t & 1) << 5;
        const float* srcp = prompt + (((size_t)b * CCH + c) << 12) + n0 + nh;
        const float* srcx = xg     + (((size_t)b * CCH + c) << 12) + n0 + nh;
        float* dp = ps + c * 64 + nh;
        float* dx = xs + c * 64 + nh;
        #pragma unroll
        for (int k = 0; k < 32; k += 4) {
            *reinterpret_cast<float4*>(dp + k) = *reinterpret_cast<const float4*>(srcp + k);
            *reinterpret_cast<float4*>(dx + k) = *reinterpret_cast<const float4*>(srcx + k);
        }
    }
    __syncthreads();

    const int co   = t & 127;
    const int half = t >> 7;
    const float4* wq4 = reinterpret_cast<const float4*>(Wq + co * CCH);
    const float4* wk4 = reinterpret_cast<const float4*>(Wk + co * CCH);
    const float4* wv4 = reinterpret_cast<const float4*>(Wv + co * CCH);
    const float bqv = bq[co], bkv = bk[co], bvv = bv[co];
    const float scale = 0.08838834764831845f;  // 1/sqrt(128)

    for (int nb = 0; nb < 32; nb += 8) {
        const int n = (half << 5) + nb;
        float aq[8] = {0,0,0,0,0,0,0,0};
        float ak[8] = {0,0,0,0,0,0,0,0};
        float av[8] = {0,0,0,0,0,0,0,0};
        for (int c4 = 0; c4 < 32; ++c4) {
            const float4 wqv = wq4[c4], wkv = wk4[c4], wvv = wv4[c4];
            #pragma unroll
            for (int cc = 0; cc < 4; ++cc) {
                const float wqc = (cc==0)?wqv.x:(cc==1)?wqv.y:(cc==2)?wqv.z:wqv.w;
                const float wkc = (cc==0)?wkv.x:(cc==1)?wkv.y:(cc==2)?wkv.z:wkv.w;
                const float wvc = (cc==0)?wvv.x:(cc==1)?wvv.y:(cc==2)?wvv.z:wvv.w;
                const float* pr = ps + (c4 * 4 + cc) * 64 + n;
                const float* xr = xs + (c4 * 4 + cc) * 64 + n;
                float pa[8], xa[8];
                *reinterpret_cast<float4*>(&pa[0]) = *reinterpret_cast<const float4*>(pr);
                *reinterpret_cast<float4*>(&pa[4]) = *reinterpret_cast<const float4*>(pr + 4);
                *reinterpret_cast<float4*>(&xa[0]) = *reinterpret_cast<const float4*>(xr);
                *reinterpret_cast<float4*>(&xa[4]) = *reinterpret_cast<const float4*>(xr + 4);
                #pragma unroll
                for (int u = 0; u < 8; ++u) {
                    aq[u] += wqc * pa[u];
                    ak[u] += wkc * xa[u];
                    av[u] += wvc * xa[u];
                }
            }
        }
        const size_t baseq = ((size_t)(b * NTOK + n0 + n)) * CCH + co;
        #pragma unroll
        for (int u = 0; u < 8; ++u) {
            Qo[baseq + (size_t)u * CCH] = f2bf((aq[u] + bqv) * scale);
            Ko[baseq + (size_t)u * CCH] = f2bf(ak[u] + bkv);
        }
        ushort8 pv;
        #pragma unroll
        for (int u = 0; u < 8; ++u) pv[u] = f2bf(av[u] + bvv);
        *reinterpret_cast<ushort8*>(Vo + (((size_t)(b * CCH + co)) << 12) + n0 + n) = pv;
    }
}

// MFMA flash attention. 256 thr = 4 waves; wave owns 16 Q-rows.
// LDS pool: Ks[64][128]bf16 swz | Vt[128][64]bf16 swz | Ps[64][64]bf16 swz | ms[64]
// All LDS rows swizzled: byte_off_in_row ^= (row&7)<<4.
__global__ __launch_bounds__(256) void attn_ln_kernel(
    const unsigned short* __restrict__ Qg, const unsigned short* __restrict__ Kg,
    const unsigned short* __restrict__ Vg,
    const int* __restrict__ maskb, const float* __restrict__ xg,
    const float* __restrict__ gamma, const float* __restrict__ beta,
    float* __restrict__ out)
{
    __shared__ __align__(16) char pool[41216];
    unsigned short* Ks = (unsigned short*)pool;              // 16384 B
    unsigned short* Vs = (unsigned short*)(pool + 16384);    // 16384 B
    unsigned short* Ps = (unsigned short*)(pool + 32768);    //  8192 B
    int*            ms = (int*)(pool + 40960);               //   256 B
    float*          stg = (float*)pool;                      // epilogue reuse

    const int t  = threadIdx.x;
    const int b  = blockIdx.x >> 6;
    const int n0 = (blockIdx.x & 63) << 6;
    const int l  = t & 63;
    const int wq = t >> 6;        // wave id: Q rows wq*16..+15
    const int g  = l >> 4;        // quarter-wave
    const int lr = l & 15;

    // Q fragments in registers: lane holds Q[n0+wq*16+lr][s*32 + g*8 + j]
    bf16x8 qf[4];
    {
        const unsigned short* qp =
            Qg + ((size_t)(b * NTOK + n0 + wq * 16 + lr)) * CCH + g * 8;
        #pragma unroll
        for (int s = 0; s < 4; ++s)
            qf[s] = *reinterpret_cast<const bf16x8*>(qp + s * 32);
    }

    f32x4 acc[8];
    float mrun[4], lrun[4];
    #pragma unroll
    for (int cf = 0; cf < 8; ++cf) acc[cf] = (f32x4){0.f, 0.f, 0.f, 0.f};
    #pragma unroll
    for (int i = 0; i < 4; ++i) { mrun[i] = -1e30f; lrun[i] = 0.f; }

    for (int kt = 0; kt < 64; ++kt) {
        const int m0 = kt << 6;
        __syncthreads();   // prev-iter LDS reads done

        {   // stage K tile 64x128 (swizzled rows of 256B)
            const int r = t >> 2, q = t & 3;
            const unsigned short* src = Kg + ((size_t)(b * NTOK + m0 + r)) * CCH + q * 32;
            char* dstrow = (char*)Ks + r * 256;
            const int swz = (r & 7) << 4;
            #pragma unroll
            for (int c = 0; c < 4; ++c)
                *reinterpret_cast<ushort8*>(dstrow + ((q * 64 + c * 16) ^ swz)) =
                    *reinterpret_cast<const ushort8*>(src + c * 8);
        }
        {   // stage V^T tile 128x64 (swizzled rows of 128B)
            const int r = t >> 1, h = t & 1;
            const unsigned short* src = Vg + ((size_t)(b * CCH + r) << 12) + m0 + h * 32;
            char* dstrow = (char*)Vs + r * 128;
            const int swz = (r & 7) << 4;
            #pragma unroll
            for (int c = 0; c < 4; ++c)
                *reinterpret_cast<ushort8*>(dstrow + ((h * 64 + c * 16) ^ swz)) =
                    *reinterpret_cast<const ushort8*>(src + c * 8);
        }
        if (t < 64) ms[t] = maskb[b * NTOK + m0 + t];
        __syncthreads();   // staged visible

        // ---- S = Q K^T : 4 col-fragments of 16, K=128 in 4 MFMA steps ----
        f32x4 sf[4];
        #pragma unroll
        for (int fc = 0; fc < 4; ++fc) {
            f32x4 a = (f32x4){0.f, 0.f, 0.f, 0.f};
            const char* rp = (const char*)(Ks + (fc * 16 + lr) * 128);
            const int swz = (lr & 7) << 4;
            #pragma unroll
            for (int s = 0; s < 4; ++s) {
                bf16x8 kb = *reinterpret_cast<const bf16x8*>(rp + ((s * 64 + g * 16) ^ swz));
                a = __builtin_amdgcn_mfma_f32_16x16x32_bf16(qf[s], kb, a, 0, 0, 0);
            }
            sf[fc] = a;
        }

        // ---- online softmax (rows r=g*4+i, wave-parallel over 16 lanes) ----
        int mkv[4];
        #pragma unroll
        for (int fc = 0; fc < 4; ++fc) mkv[fc] = ms[fc * 16 + lr];

        #pragma unroll
        for (int i = 0; i < 4; ++i) {
            float s0 = mkv[0] ? sf[0][i] : -1e30f;
            float s1 = mkv[1] ? sf[1][i] : -1e30f;
            float s2 = mkv[2] ? sf[2][i] : -1e30f;
            float s3 = mkv[3] ? sf[3][i] : -1e30f;
            float rm = fmaxf(fmaxf(s0, s1), fmaxf(s2, s3));
            rm = fmaxf(rm, __shfl_xor(rm, 1));
            rm = fmaxf(rm, __shfl_xor(rm, 2));
            rm = fmaxf(rm, __shfl_xor(rm, 4));
            rm = fmaxf(rm, __shfl_xor(rm, 8));
            const float mn = fmaxf(mrun[i], rm);
            const float cr = __expf(mrun[i] - mn);
            const float p0 = __expf(s0 - mn);
            const float p1 = __expf(s1 - mn);
            const float p2 = __expf(s2 - mn);
            const float p3 = __expf(s3 - mn);
            float rs = p0 + p1 + p2 + p3;
            rs += __shfl_xor(rs, 1);
            rs += __shfl_xor(rs, 2);
            rs += __shfl_xor(rs, 4);
            rs += __shfl_xor(rs, 8);
            mrun[i] = mn;
            lrun[i] = lrun[i] * cr + rs;
            #pragma unroll
            for (int cf = 0; cf < 8; ++cf) acc[cf][i] *= cr;
            // write P row (own-wave region; no barrier needed before PV)
            const int prow = wq * 16 + g * 4 + i;
            char* pb = (char*)Ps + prow * 128;
            const int pswz = ((g * 4 + i) & 7) << 4;
            *reinterpret_cast<unsigned short*>(pb + ((lr * 2      ) ^ pswz)) = f2bf(p0);
            *reinterpret_cast<unsigned short*>(pb + ((32 + lr * 2 ) ^ pswz)) = f2bf(p1);
            *reinterpret_cast<unsigned short*>(pb + ((64 + lr * 2 ) ^ pswz)) = f2bf(p2);
            *reinterpret_cast<unsigned short*>(pb + ((96 + lr * 2 ) ^ pswz)) = f2bf(p3);
        }

        // ---- O += P V : 8 col-fragments of 16, m=64 in 2 MFMA steps ----
        const char* prp = (const char*)(Ps + (wq * 16 + lr) * 64);
        const int aswz = (lr & 7) << 4;
        #pragma unroll
        for (int msd = 0; msd < 2; ++msd) {
            bf16x8 pa = *reinterpret_cast<const bf16x8*>(prp + ((msd * 64 + g * 16) ^ aswz));
            #pragma unroll
            for (int cf = 0; cf < 8; ++cf) {
                const char* vrp = (const char*)(Vs + (cf * 16 + lr) * 64);
                bf16x8 vb = *reinterpret_cast<const bf16x8*>(vrp + ((msd * 64 + g * 16) ^ aswz));
                acc[cf] = __builtin_amdgcn_mfma_f32_16x16x32_bf16(pa, vb, acc[cf], 0, 0, 0);
            }
        }
    }

    // ---------------- epilogue: residual + LayerNorm + transpose ----------------
    __syncthreads();
    {   // stage x tile (c-major) for residual: stg[c][n], stride 65
        const int c = t >> 1, nh = (t & 1) << 5;
        const float* src = xg + (((size_t)b * CCH + c) << 12) + n0 + nh;
        float* dst = stg + c * 65 + nh;
        #pragma unroll
        for (int k = 0; k < 32; k += 4) {
            const float4 v = *reinterpret_cast<const float4*>(src + k);
            dst[k] = v.x; dst[k+1] = v.y; dst[k+2] = v.z; dst[k+3] = v.w;
        }
    }
    __syncthreads();

    float g8[8], b8[8];
    #pragma unroll
    for (int cf = 0; cf < 8; ++cf) {
        g8[cf] = gamma[cf * 16 + lr];
        b8[cf] = beta[cf * 16 + lr];
    }

    #pragma unroll
    for (int i = 0; i < 4; ++i) {
        const float inv = 1.f / lrun[i];
        const int nloc = wq * 16 + g * 4 + i;
        float sum = 0.f, sq = 0.f;
        #pragma unroll
        for (int cf = 0; cf < 8; ++cf) {
            const float v = acc[cf][i] * inv + stg[(cf * 16 + lr) * 65 + nloc];
            acc[cf][i] = v; sum += v; sq += v * v;
        }
        sum += __shfl_xor(sum, 1); sq += __shfl_xor(sq, 1);
        sum += __shfl_xor(sum, 2); sq += __shfl_xor(sq, 2);
        sum += __shfl_xor(sum, 4); sq += __shfl_xor(sq, 4);
        sum += __shfl_xor(sum, 8); sq += __shfl_xor(sq, 8);
        const float mean = sum * (1.f / 128.f);
        const float var  = sq * (1.f / 128.f) - mean * mean;
        const float rstd = rsqrtf(var + 1e-5f);
        #pragma unroll
        for (int cf = 0; cf < 8; ++cf)
            acc[cf][i] = (acc[cf][i] - mean) * rstd * g8[cf] + b8[cf];
    }
    __syncthreads();   // residual reads of stg done

    #pragma unroll
    for (int i = 0; i < 4; ++i) {
        #pragma unroll
        for (int cf = 0; cf < 8; ++cf)
            stg[(cf * 16 + lr) * 65 + wq * 16 + g * 4 + i] = acc[cf][i];
    }
    __syncthreads();

    {   // coalesced transposed store
        const int c = t >> 1, nh = (t & 1) << 5;
        float* dst = out + (((size_t)b * CCH + c) << 12) + n0 + nh;
        const float* srcl = stg + c * 65 + nh;
        #pragma unroll
        for (int k = 0; k < 32; k += 4) {
            float4 v; v.x = srcl[k]; v.y = srcl[k+1]; v.z = srcl[k+2]; v.w = srcl[k+3];
            *reinterpret_cast<float4*>(dst + k) = v;
        }
    }
}

extern "C" void kernel_launch(void* const* d_in, const int* in_sizes, int n_in,
                              void* d_out, int out_size, void* d_ws, size_t ws_size,
                              hipStream_t stream) {
    const float* prompt = (const float*)d_in[0];
    const float* x      = (const float*)d_in[1];
    const float* Wq     = (const float*)d_in[2];
    const float* bq     = (const float*)d_in[3];
    const float* Wk     = (const float*)d_in[4];
    const float* bk     = (const float*)d_in[5];
    const float* Wv     = (const float*)d_in[6];
    const float* bv     = (const float*)d_in[7];
    const float* gamma  = (const float*)d_in[8];
    const float* beta   = (const float*)d_in[9];
    const int*   maskb  = (const int*)d_in[10];
    float* out = (float*)d_out;

    const size_t M = (size_t)4 * NTOK * CCH;   // 2,097,152 elems
    unsigned short* Qw = (unsigned short*)d_ws;
    unsigned short* Kw = Qw + M;
    unsigned short* Vw = Kw + M;

    qkv_kernel<<<256, 256, 0, stream>>>(prompt, x, Wq, bq, Wk, bk, Wv, bv, Qw, Kw, Vw);
    attn_ln_kernel<<<256, 256, 0, stream>>>(Qw, Kw, Vw, maskb, x, gamma, beta, out);
}

// Round 3
// 215.929 us; speedup vs baseline: 5.1562x; 1.2510x over previous
//
#include <hip/hip_runtime.h>

// MaskAttention: B=4, C=128, H=W=64 -> N=4096
// Round 3: pipelined staging.
//   k1: QKV fp32 -> ws bf16 (Q pre-scaled). 32-token tiles, grid 512, padded LDS.
//   k2: MFMA flash attention, K/V double-buffered via global_load_lds (pre-swizzled
//       source, linear dest), counted vmcnt, raw s_barrier. + residual + LN.

#define CCH 128
#define NTOK 4096

typedef __attribute__((ext_vector_type(8))) short  bf16x8;
typedef __attribute__((ext_vector_type(8))) unsigned short ushort8;
typedef __attribute__((ext_vector_type(4))) float  f32x4;

__device__ __forceinline__ unsigned short f2bf(float f) {
    unsigned int u = __builtin_bit_cast(unsigned int, f);
    u += 0x7FFFu + ((u >> 16) & 1u);      // RNE (finite inputs)
    return (unsigned short)(u >> 16);
}

__device__ __forceinline__ void gload_lds16(const void* g, void* l) {
    __builtin_amdgcn_global_load_lds(
        (const __attribute__((address_space(1))) unsigned int*)g,
        (__attribute__((address_space(3))) unsigned int*)l, 16, 0, 0);
}

// ---------------- k1: QKV projections ----------------
__global__ __launch_bounds__(256) void qkv_kernel(
    const float* __restrict__ prompt, const float* __restrict__ xg,
    const float* __restrict__ Wq, const float* __restrict__ bq,
    const float* __restrict__ Wk, const float* __restrict__ bk,
    const float* __restrict__ Wv, const float* __restrict__ bv,
    unsigned short* __restrict__ Qo, unsigned short* __restrict__ Ko,
    unsigned short* __restrict__ Vo)
{
    __shared__ float ps[128 * 36];   // padded stride 36 (aligned, conflict-spread)
    __shared__ float xs[128 * 36];
    const int t  = threadIdx.x;
    const int b  = blockIdx.x >> 7;
    const int n0 = (blockIdx.x & 127) << 5;   // 32-token tile

    {   // stage: thread t -> row c = t>>1, 16 floats at col (t&1)*16
        const int c = t >> 1, h0 = (t & 1) << 4;
        const float* srcp = prompt + (((size_t)b * CCH + c) << 12) + n0 + h0;
        const float* srcx = xg     + (((size_t)b * CCH + c) << 12) + n0 + h0;
        float* dp = ps + c * 36 + h0;
        float* dx = xs + c * 36 + h0;
        #pragma unroll
        for (int k = 0; k < 16; k += 4) {
            *reinterpret_cast<float4*>(dp + k) = *reinterpret_cast<const float4*>(srcp + k);
            *reinterpret_cast<float4*>(dx + k) = *reinterpret_cast<const float4*>(srcx + k);
        }
    }
    __syncthreads();

    const int co   = t & 127;
    const int half = t >> 7;                  // tokens 0-15 / 16-31
    const float4* wq4 = reinterpret_cast<const float4*>(Wq + co * CCH);
    const float4* wk4 = reinterpret_cast<const float4*>(Wk + co * CCH);
    const float4* wv4 = reinterpret_cast<const float4*>(Wv + co * CCH);
    const float bqv = bq[co], bkv = bk[co], bvv = bv[co];
    const float scale = 0.08838834764831845f;  // 1/sqrt(128)

    for (int nb = 0; nb < 16; nb += 8) {
        const int n = (half << 4) + nb;
        float aq[8] = {0,0,0,0,0,0,0,0};
        float ak[8] = {0,0,0,0,0,0,0,0};
        float av[8] = {0,0,0,0,0,0,0,0};
        for (int c4 = 0; c4 < 32; ++c4) {
            const float4 wqv = wq4[c4], wkv = wk4[c4], wvv = wv4[c4];
            #pragma unroll
            for (int cc = 0; cc < 4; ++cc) {
                const float wqc = (cc==0)?wqv.x:(cc==1)?wqv.y:(cc==2)?wqv.z:wqv.w;
                const float wkc = (cc==0)?wkv.x:(cc==1)?wkv.y:(cc==2)?wkv.z:wkv.w;
                const float wvc = (cc==0)?wvv.x:(cc==1)?wvv.y:(cc==2)?wvv.z:wvv.w;
                const float* pr = ps + (c4 * 4 + cc) * 36 + n;
                const float* xr = xs + (c4 * 4 + cc) * 36 + n;
                float pa[8], xa[8];
                *reinterpret_cast<float4*>(&pa[0]) = *reinterpret_cast<const float4*>(pr);
                *reinterpret_cast<float4*>(&pa[4]) = *reinterpret_cast<const float4*>(pr + 4);
                *reinterpret_cast<float4*>(&xa[0]) = *reinterpret_cast<const float4*>(xr);
                *reinterpret_cast<float4*>(&xa[4]) = *reinterpret_cast<const float4*>(xr + 4);
                #pragma unroll
                for (int u = 0; u < 8; ++u) {
                    aq[u] += wqc * pa[u];
                    ak[u] += wkc * xa[u];
                    av[u] += wvc * xa[u];
                }
            }
        }
        const size_t baseq = ((size_t)(b * NTOK + n0 + n)) * CCH + co;
        #pragma unroll
        for (int u = 0; u < 8; ++u) {
            Qo[baseq + (size_t)u * CCH] = f2bf((aq[u] + bqv) * scale);
            Ko[baseq + (size_t)u * CCH] = f2bf(ak[u] + bkv);
        }
        ushort8 pv;
        #pragma unroll
        for (int u = 0; u < 8; ++u) pv[u] = f2bf(av[u] + bvv);
        *reinterpret_cast<ushort8*>(Vo + (((size_t)(b * CCH + co)) << 12) + n0 + n) = pv;
    }
}

// ---------------- k2: attention ----------------
// LDS pool (dynamic, 73728 B):
//   Ks[2]: [0,16384),[16384,32768)   64 rows x 256B, swizzled chunks
//   Vs[2]: [32768,49152),[49152,65536) 128 rows x 128B, swizzled chunks
//   Ps   : [65536,73728)             64 rows x 128B
// Swizzle: 16B-chunk index ^= (row & 7). Staged with linear LDS dest +
// pre-swizzled global source (global_load_lds writes base + lane*16).
__device__ __forceinline__ void stage_tile(
    const unsigned short* __restrict__ Kg, const unsigned short* __restrict__ Vg,
    char* KsB, char* VsB, int b, int m0, int wq, int l)
{
    #pragma unroll
    for (int ii = 0; ii < 4; ++ii) {        // K: 4 chunks of 1KB (4 rows each)
        const int i = wq * 4 + ii;
        const int r = i * 4 + (l >> 4);
        const int csrc = (l & 15) ^ (r & 7);
        const unsigned short* src = Kg + ((size_t)(b * NTOK + m0 + r) << 7) + csrc * 8;
        gload_lds16(src, KsB + i * 1024);
    }
    #pragma unroll
    for (int ii = 0; ii < 4; ++ii) {        // V: 4 chunks of 1KB (8 rows each)
        const int i = wq * 4 + ii;
        const int r = i * 8 + (l >> 3);
        const int csrc = (l & 7) ^ (r & 7);
        const unsigned short* src = Vg + ((size_t)(b * CCH + r) << 12) + m0 + csrc * 8;
        gload_lds16(src, VsB + i * 1024);
    }
}

__global__ __launch_bounds__(256) void attn_ln_kernel(
    const unsigned short* __restrict__ Qg, const unsigned short* __restrict__ Kg,
    const unsigned short* __restrict__ Vg,
    const int* __restrict__ maskb, const float* __restrict__ xg,
    const float* __restrict__ gamma, const float* __restrict__ beta,
    float* __restrict__ out)
{
    extern __shared__ __align__(16) char pool[];
    char* KsBuf = pool;
    char* VsBuf = pool + 32768;
    unsigned short* Ps = (unsigned short*)(pool + 65536);
    float* stg = (float*)pool;   // epilogue reuse

    // XCD-bijective swizzle: batch b -> 2 XCDs, so K+V (2MB) fits 4MB L2.
    const int bid = (blockIdx.x & 7) * 32 + (blockIdx.x >> 3);
    const int t  = threadIdx.x;
    const int b  = bid >> 6;
    const int n0 = (bid & 63) << 6;
    const int l  = t & 63;
    const int wq = t >> 6;
    const int g  = l >> 4;
    const int lr = l & 15;

    // Q fragments: lane holds Q[n0+wq*16+lr][s*32 + g*8 + j]
    bf16x8 qf[4];
    {
        const unsigned short* qp =
            Qg + ((size_t)(b * NTOK + n0 + wq * 16 + lr)) * CCH + g * 8;
        #pragma unroll
        for (int s = 0; s < 4; ++s)
            qf[s] = *reinterpret_cast<const bf16x8*>(qp + s * 32);
    }

    f32x4 acc[8];
    float mrun[4], lrun[4];
    #pragma unroll
    for (int cf = 0; cf < 8; ++cf) acc[cf] = (f32x4){0.f, 0.f, 0.f, 0.f};
    #pragma unroll
    for (int i = 0; i < 4; ++i) { mrun[i] = -1e30f; lrun[i] = 0.f; }

    stage_tile(Kg, Vg, KsBuf, VsBuf, b, 0, wq, l);   // tile 0 -> buf 0

    for (int kt = 0; kt < 64; ++kt) {
        __builtin_amdgcn_s_barrier();        // [A] prev compute reads done
        __builtin_amdgcn_sched_barrier(0);

        const int m0 = kt << 6;
        int mk[4];
        #pragma unroll
        for (int fc = 0; fc < 4; ++fc)
            mk[fc] = maskb[(size_t)b * NTOK + m0 + fc * 16 + lr];

        const int tn = (kt + 1) & 63;        // prefetch next tile (wraps, harmless)
        stage_tile(Kg, Vg, KsBuf + (tn & 1) * 16384, VsBuf + (tn & 1) * 16384,
                   b, tn << 6, wq, l);

        asm volatile("s_waitcnt vmcnt(12)" ::: "memory");  // own stage(kt) drained
        __builtin_amdgcn_sched_barrier(0);
        __builtin_amdgcn_s_barrier();        // [B] everyone's stage(kt) visible
        __builtin_amdgcn_sched_barrier(0);

        const char* Ks_c = KsBuf + (kt & 1) * 16384;
        const char* Vs_c = VsBuf + (kt & 1) * 16384;
        const int swz = (lr & 7) << 4;

        // ---- S = Q K^T ----
        f32x4 sf[4];
        #pragma unroll
        for (int fc = 0; fc < 4; ++fc) {
            f32x4 a = (f32x4){0.f, 0.f, 0.f, 0.f};
            const char* rp = Ks_c + (fc * 16 + lr) * 256;
            #pragma unroll
            for (int s = 0; s < 4; ++s) {
                bf16x8 kb = *reinterpret_cast<const bf16x8*>(rp + ((s * 64 + g * 16) ^ swz));
                a = __builtin_amdgcn_mfma_f32_16x16x32_bf16(qf[s], kb, a, 0, 0, 0);
            }
            sf[fc] = a;
        }

        // ---- online softmax ----
        #pragma unroll
        for (int i = 0; i < 4; ++i) {
            float s0 = mk[0] ? sf[0][i] : -1e30f;
            float s1 = mk[1] ? sf[1][i] : -1e30f;
            float s2 = mk[2] ? sf[2][i] : -1e30f;
            float s3 = mk[3] ? sf[3][i] : -1e30f;
            float rm = fmaxf(fmaxf(s0, s1), fmaxf(s2, s3));
            rm = fmaxf(rm, __shfl_xor(rm, 1));
            rm = fmaxf(rm, __shfl_xor(rm, 2));
            rm = fmaxf(rm, __shfl_xor(rm, 4));
            rm = fmaxf(rm, __shfl_xor(rm, 8));
            const float mn = fmaxf(mrun[i], rm);
            const float cr = __expf(mrun[i] - mn);
            const float p0 = __expf(s0 - mn);
            const float p1 = __expf(s1 - mn);
            const float p2 = __expf(s2 - mn);
            const float p3 = __expf(s3 - mn);
            float rs = p0 + p1 + p2 + p3;
            rs += __shfl_xor(rs, 1);
            rs += __shfl_xor(rs, 2);
            rs += __shfl_xor(rs, 4);
            rs += __shfl_xor(rs, 8);
            mrun[i] = mn;
            lrun[i] = lrun[i] * cr + rs;
            #pragma unroll
            for (int cf = 0; cf < 8; ++cf) acc[cf][i] *= cr;
            const int prow = wq * 16 + g * 4 + i;
            char* pb = (char*)Ps + prow * 128;
            const int pswz = ((g * 4 + i) & 7) << 4;
            *reinterpret_cast<unsigned short*>(pb + ((lr * 2      ) ^ pswz)) = f2bf(p0);
            *reinterpret_cast<unsigned short*>(pb + ((32 + lr * 2 ) ^ pswz)) = f2bf(p1);
            *reinterpret_cast<unsigned short*>(pb + ((64 + lr * 2 ) ^ pswz)) = f2bf(p2);
            *reinterpret_cast<unsigned short*>(pb + ((96 + lr * 2 ) ^ pswz)) = f2bf(p3);
        }

        // ---- O += P V ----
        const char* prp = (const char*)Ps + (wq * 16 + lr) * 128;
        #pragma unroll
        for (int msd = 0; msd < 2; ++msd) {
            bf16x8 pa = *reinterpret_cast<const bf16x8*>(prp + ((msd * 64 + g * 16) ^ swz));
            #pragma unroll
            for (int cf = 0; cf < 8; ++cf) {
                const char* vrp = Vs_c + (cf * 16 + lr) * 128;
                bf16x8 vb = *reinterpret_cast<const bf16x8*>(vrp + ((msd * 64 + g * 16) ^ swz));
                acc[cf] = __builtin_amdgcn_mfma_f32_16x16x32_bf16(pa, vb, acc[cf], 0, 0, 0);
            }
        }
    }

    // ---------------- epilogue: residual + LayerNorm + transpose ----------------
    __syncthreads();
    {   // stage x tile (c-major), stride 65
        const int c = t >> 1, nh = (t & 1) << 5;
        const float* src = xg + (((size_t)b * CCH + c) << 12) + n0 + nh;
        float* dst = stg + c * 65 + nh;
        #pragma unroll
        for (int k = 0; k < 32; k += 4) {
            const float4 v = *reinterpret_cast<const float4*>(src + k);
            dst[k] = v.x; dst[k+1] = v.y; dst[k+2] = v.z; dst[k+3] = v.w;
        }
    }
    __syncthreads();

    float g8[8], b8[8];
    #pragma unroll
    for (int cf = 0; cf < 8; ++cf) {
        g8[cf] = gamma[cf * 16 + lr];
        b8[cf] = beta[cf * 16 + lr];
    }

    #pragma unroll
    for (int i = 0; i < 4; ++i) {
        const float inv = 1.f / lrun[i];
        const int nloc = wq * 16 + g * 4 + i;
        float sum = 0.f, sq = 0.f;
        #pragma unroll
        for (int cf = 0; cf < 8; ++cf) {
            const float v = acc[cf][i] * inv + stg[(cf * 16 + lr) * 65 + nloc];
            acc[cf][i] = v; sum += v; sq += v * v;
        }
        sum += __shfl_xor(sum, 1); sq += __shfl_xor(sq, 1);
        sum += __shfl_xor(sum, 2); sq += __shfl_xor(sq, 2);
        sum += __shfl_xor(sum, 4); sq += __shfl_xor(sq, 4);
        sum += __shfl_xor(sum, 8); sq += __shfl_xor(sq, 8);
        const float mean = sum * (1.f / 128.f);
        const float var  = sq * (1.f / 128.f) - mean * mean;
        const float rstd = rsqrtf(var + 1e-5f);
        #pragma unroll
        for (int cf = 0; cf < 8; ++cf)
            acc[cf][i] = (acc[cf][i] - mean) * rstd * g8[cf] + b8[cf];
    }
    __syncthreads();

    #pragma unroll
    for (int i = 0; i < 4; ++i) {
        #pragma unroll
        for (int cf = 0; cf < 8; ++cf)
            stg[(cf * 16 + lr) * 65 + wq * 16 + g * 4 + i] = acc[cf][i];
    }
    __syncthreads();

    {   // coalesced transposed store
        const int c = t >> 1, nh = (t & 1) << 5;
        float* dst = out + (((size_t)b * CCH + c) << 12) + n0 + nh;
        const float* srcl = stg + c * 65 + nh;
        #pragma unroll
        for (int k = 0; k < 32; k += 4) {
            float4 v; v.x = srcl[k]; v.y = srcl[k+1]; v.z = srcl[k+2]; v.w = srcl[k+3];
            *reinterpret_cast<float4*>(dst + k) = v;
        }
    }
}

extern "C" void kernel_launch(void* const* d_in, const int* in_sizes, int n_in,
                              void* d_out, int out_size, void* d_ws, size_t ws_size,
                              hipStream_t stream) {
    const float* prompt = (const float*)d_in[0];
    const float* x      = (const float*)d_in[1];
    const float* Wq     = (const float*)d_in[2];
    const float* bq     = (const float*)d_in[3];
    const float* Wk     = (const float*)d_in[4];
    const float* bk     = (const float*)d_in[5];
    const float* Wv     = (const float*)d_in[6];
    const float* bv     = (const float*)d_in[7];
    const float* gamma  = (const float*)d_in[8];
    const float* beta   = (const float*)d_in[9];
    const int*   maskb  = (const int*)d_in[10];
    float* out = (float*)d_out;

    const size_t M = (size_t)4 * NTOK * CCH;
    unsigned short* Qw = (unsigned short*)d_ws;
    unsigned short* Kw = Qw + M;
    unsigned short* Vw = Kw + M;

    qkv_kernel<<<512, 256, 0, stream>>>(prompt, x, Wq, bq, Wk, bk, Wv, bv, Qw, Kw, Vw);
    attn_ln_kernel<<<256, 256, 73728, stream>>>(Qw, Kw, Vw, maskb, x, gamma, beta, out);
}

// Round 4
// 163.325 us; speedup vs baseline: 6.8169x; 1.3221x over previous
//
#include <hip/hip_runtime.h>

// MaskAttention: B=4, C=128, H=W=64 -> N=4096
// Round 4: occupancy. attn = 512-thread blocks, in-block K-split (waves 0-3 keys
// [0,2048), waves 4-7 keys [2048,4096)), LDS merge, fused residual+LN epilogue.
// qkv = 16-token tiles, grid 1024.

#define CCH 128
#define NTOK 4096

typedef __attribute__((ext_vector_type(8))) short  bf16x8;
typedef __attribute__((ext_vector_type(8))) unsigned short ushort8;
typedef __attribute__((ext_vector_type(4))) float  f32x4;

__device__ __forceinline__ unsigned short f2bf(float f) {
    unsigned int u = __builtin_bit_cast(unsigned int, f);
    u += 0x7FFFu + ((u >> 16) & 1u);      // RNE (finite inputs)
    return (unsigned short)(u >> 16);
}

__device__ __forceinline__ void gload_lds16(const void* g, void* l) {
    __builtin_amdgcn_global_load_lds(
        (const __attribute__((address_space(1))) unsigned int*)g,
        (__attribute__((address_space(3))) unsigned int*)l, 16, 0, 0);
}

// ---------------- k1: QKV projections (16-token tiles, grid 1024) ----------------
__global__ __launch_bounds__(256) void qkv_kernel(
    const float* __restrict__ prompt, const float* __restrict__ xg,
    const float* __restrict__ Wq, const float* __restrict__ bq,
    const float* __restrict__ Wk, const float* __restrict__ bk,
    const float* __restrict__ Wv, const float* __restrict__ bv,
    unsigned short* __restrict__ Qo, unsigned short* __restrict__ Ko,
    unsigned short* __restrict__ Vo)
{
    __shared__ float ps[128 * 20];   // stride 20 (odd-ish: conflict-spread, aligned enough)
    __shared__ float xs[128 * 20];
    const int t  = threadIdx.x;
    const int b  = blockIdx.x >> 8;
    const int n0 = (blockIdx.x & 255) << 4;   // 16-token tile

    {   // stage: thread t -> row c = t>>1, 8 floats at (t&1)*8
        const int c = t >> 1, h0 = (t & 1) << 3;
        const float* srcp = prompt + (((size_t)b * CCH + c) << 12) + n0 + h0;
        const float* srcx = xg     + (((size_t)b * CCH + c) << 12) + n0 + h0;
        float* dp = ps + c * 20 + h0;
        float* dx = xs + c * 20 + h0;
        *reinterpret_cast<float4*>(dp)     = *reinterpret_cast<const float4*>(srcp);
        *reinterpret_cast<float4*>(dp + 4) = *reinterpret_cast<const float4*>(srcp + 4);
        *reinterpret_cast<float4*>(dx)     = *reinterpret_cast<const float4*>(srcx);
        *reinterpret_cast<float4*>(dx + 4) = *reinterpret_cast<const float4*>(srcx + 4);
    }
    __syncthreads();

    const int co   = t & 127;
    const int half = t >> 7;                  // tokens 0-7 / 8-15
    const int nb   = half << 3;
    const float4* wq4 = reinterpret_cast<const float4*>(Wq + co * CCH);
    const float4* wk4 = reinterpret_cast<const float4*>(Wk + co * CCH);
    const float4* wv4 = reinterpret_cast<const float4*>(Wv + co * CCH);
    const float bqv = bq[co], bkv = bk[co], bvv = bv[co];
    const float scale = 0.08838834764831845f;  // 1/sqrt(128)

    float aq[8] = {0,0,0,0,0,0,0,0};
    float ak[8] = {0,0,0,0,0,0,0,0};
    float av[8] = {0,0,0,0,0,0,0,0};
    for (int c4 = 0; c4 < 32; ++c4) {
        const float4 wqv = wq4[c4], wkv = wk4[c4], wvv = wv4[c4];
        #pragma unroll
        for (int cc = 0; cc < 4; ++cc) {
            const float wqc = (cc==0)?wqv.x:(cc==1)?wqv.y:(cc==2)?wqv.z:wqv.w;
            const float wkc = (cc==0)?wkv.x:(cc==1)?wkv.y:(cc==2)?wkv.z:wkv.w;
            const float wvc = (cc==0)?wvv.x:(cc==1)?wvv.y:(cc==2)?wvv.z:wvv.w;
            const float* pr = ps + (c4 * 4 + cc) * 20 + nb;
            const float* xr = xs + (c4 * 4 + cc) * 20 + nb;
            float pa[8], xa[8];
            *reinterpret_cast<float4*>(&pa[0]) = *reinterpret_cast<const float4*>(pr);
            *reinterpret_cast<float4*>(&pa[4]) = *reinterpret_cast<const float4*>(pr + 4);
            *reinterpret_cast<float4*>(&xa[0]) = *reinterpret_cast<const float4*>(xr);
            *reinterpret_cast<float4*>(&xa[4]) = *reinterpret_cast<const float4*>(xr + 4);
            #pragma unroll
            for (int u = 0; u < 8; ++u) {
                aq[u] += wqc * pa[u];
                ak[u] += wkc * xa[u];
                av[u] += wvc * xa[u];
            }
        }
    }
    const size_t baseq = ((size_t)(b * NTOK + n0 + nb)) * CCH + co;
    #pragma unroll
    for (int u = 0; u < 8; ++u) {
        Qo[baseq + (size_t)u * CCH] = f2bf((aq[u] + bqv) * scale);
        Ko[baseq + (size_t)u * CCH] = f2bf(ak[u] + bkv);
    }
    ushort8 pv;
    #pragma unroll
    for (int u = 0; u < 8; ++u) pv[u] = f2bf(av[u] + bvv);
    *reinterpret_cast<ushort8*>(Vo + (((size_t)(b * CCH + co)) << 12) + n0 + nb) = pv;
}

// ---------------- k2: attention (8 waves, in-block K-split) ----------------
// Dynamic LDS pool (147456 B):
//   Ks half0: [0,32K)  half1: [32K,64K)     (each: dbuf 2 x 16384, 64 rows x 256B swz)
//   Vs half0: [64K,96K) half1: [96K,128K)   (each: dbuf 2 x 16384, 128 rows x 128B swz)
//   Ps      : [128K,144K)                    (8 waves x 16 rows x 128B)
//   merge   : [0,42K)      reused post-loop  (4 waves x 64 lanes x 41 floats)
//   stg     : [48K,81.5K)  x c-major 128x65 f32
//   tstg    : [84K,117K)   out  c-major 128x65 f32
__device__ __forceinline__ void stage_tile(
    const unsigned short* __restrict__ Kg, const unsigned short* __restrict__ Vg,
    char* KsB, char* VsB, int b, int m0, int w4, int l)
{
    #pragma unroll
    for (int ii = 0; ii < 4; ++ii) {        // K: 4 chunks of 1KB (4 rows each)
        const int i = w4 * 4 + ii;
        const int r = i * 4 + (l >> 4);
        const int csrc = (l & 15) ^ (r & 7);
        const unsigned short* src = Kg + ((size_t)(b * NTOK + m0 + r) << 7) + csrc * 8;
        gload_lds16(src, KsB + i * 1024);
    }
    #pragma unroll
    for (int ii = 0; ii < 4; ++ii) {        // V: 4 chunks of 1KB (8 rows each)
        const int i = w4 * 4 + ii;
        const int r = i * 8 + (l >> 3);
        const int csrc = (l & 7) ^ (r & 7);
        const unsigned short* src = Vg + ((size_t)(b * CCH + r) << 12) + m0 + csrc * 8;
        gload_lds16(src, VsB + i * 1024);
    }
}

__global__ __launch_bounds__(512) void attn_ln_kernel(
    const unsigned short* __restrict__ Qg, const unsigned short* __restrict__ Kg,
    const unsigned short* __restrict__ Vg,
    const int* __restrict__ maskb, const float* __restrict__ xg,
    const float* __restrict__ gamma, const float* __restrict__ beta,
    float* __restrict__ out)
{
    extern __shared__ __align__(16) char pool[];
    unsigned short* Ps = (unsigned short*)(pool + 131072);
    float* mrg  = (float*)pool;
    float* stg  = (float*)(pool + 49152);
    float* tstg = (float*)(pool + 86016);

    // XCD swizzle: batch -> 2 XCDs so K+V (2MB/batch) sits in per-XCD L2.
    const int bid = (blockIdx.x & 7) * 32 + (blockIdx.x >> 3);
    const int t  = threadIdx.x;
    const int b  = bid >> 6;
    const int n0 = (bid & 63) << 6;
    const int l  = t & 63;
    const int wq = t >> 6;        // 0..7
    const int h  = wq >> 2;       // K-half
    const int w4 = wq & 3;        // Q-row group
    const int g  = l >> 4;
    const int lr = l & 15;
    const int base_m = h << 11;   // h * 2048

    char* KsH = pool + h * 32768;
    char* VsH = pool + 65536 + h * 32768;

    // Q fragments: lane holds Q[n0+w4*16+lr][s*32 + g*8 + j]
    bf16x8 qf[4];
    {
        const unsigned short* qp =
            Qg + ((size_t)(b * NTOK + n0 + w4 * 16 + lr)) * CCH + g * 8;
        #pragma unroll
        for (int s = 0; s < 4; ++s)
            qf[s] = *reinterpret_cast<const bf16x8*>(qp + s * 32);
    }

    f32x4 acc[8];
    float mrun[4], lrun[4];
    #pragma unroll
    for (int cf = 0; cf < 8; ++cf) acc[cf] = (f32x4){0.f, 0.f, 0.f, 0.f};
    #pragma unroll
    for (int i = 0; i < 4; ++i) { mrun[i] = -1e30f; lrun[i] = 0.f; }

    stage_tile(Kg, Vg, KsH, VsH, b, base_m, w4, l);   // tile 0 of this half

    for (int it = 0; it < 32; ++it) {
        __builtin_amdgcn_s_barrier();        // [A] prev compute reads done
        __builtin_amdgcn_sched_barrier(0);

        const int m0 = base_m + (it << 6);
        int mk[4];
        #pragma unroll
        for (int fc = 0; fc < 4; ++fc)
            mk[fc] = maskb[(size_t)b * NTOK + m0 + fc * 16 + lr];

        const int tn = (it + 1) & 31;        // wraps to restage tile 0: harmless
        stage_tile(Kg, Vg, KsH + (tn & 1) * 16384, VsH + (tn & 1) * 16384,
                   b, base_m + (tn << 6), w4, l);

        asm volatile("s_waitcnt vmcnt(12)" ::: "memory");  // own stage(it) drained
        __builtin_amdgcn_sched_barrier(0);
        __builtin_amdgcn_s_barrier();        // [B] stage(it) visible block-wide
        __builtin_amdgcn_sched_barrier(0);

        const char* Ks_c = KsH + (it & 1) * 16384;
        const char* Vs_c = VsH + (it & 1) * 16384;
        const int swz = (lr & 7) << 4;

        // ---- S = Q K^T ----
        f32x4 sf[4];
        #pragma unroll
        for (int fc = 0; fc < 4; ++fc) {
            f32x4 a = (f32x4){0.f, 0.f, 0.f, 0.f};
            const char* rp = Ks_c + (fc * 16 + lr) * 256;
            #pragma unroll
            for (int s = 0; s < 4; ++s) {
                bf16x8 kb = *reinterpret_cast<const bf16x8*>(rp + ((s * 64 + g * 16) ^ swz));
                a = __builtin_amdgcn_mfma_f32_16x16x32_bf16(qf[s], kb, a, 0, 0, 0);
            }
            sf[fc] = a;
        }

        // ---- online softmax ----
        #pragma unroll
        for (int i = 0; i < 4; ++i) {
            float s0 = mk[0] ? sf[0][i] : -1e30f;
            float s1 = mk[1] ? sf[1][i] : -1e30f;
            float s2 = mk[2] ? sf[2][i] : -1e30f;
            float s3 = mk[3] ? sf[3][i] : -1e30f;
            float rm = fmaxf(fmaxf(s0, s1), fmaxf(s2, s3));
            rm = fmaxf(rm, __shfl_xor(rm, 1));
            rm = fmaxf(rm, __shfl_xor(rm, 2));
            rm = fmaxf(rm, __shfl_xor(rm, 4));
            rm = fmaxf(rm, __shfl_xor(rm, 8));
            const float mn = fmaxf(mrun[i], rm);
            const float cr = __expf(mrun[i] - mn);
            const float p0 = __expf(s0 - mn);
            const float p1 = __expf(s1 - mn);
            const float p2 = __expf(s2 - mn);
            const float p3 = __expf(s3 - mn);
            float rs = p0 + p1 + p2 + p3;
            rs += __shfl_xor(rs, 1);
            rs += __shfl_xor(rs, 2);
            rs += __shfl_xor(rs, 4);
            rs += __shfl_xor(rs, 8);
            mrun[i] = mn;
            lrun[i] = lrun[i] * cr + rs;
            #pragma unroll
            for (int cf = 0; cf < 8; ++cf) acc[cf][i] *= cr;
            const int prow = wq * 16 + g * 4 + i;
            char* pb = (char*)Ps + prow * 128;
            const int pswz = ((g * 4 + i) & 7) << 4;
            *reinterpret_cast<unsigned short*>(pb + ((lr * 2      ) ^ pswz)) = f2bf(p0);
            *reinterpret_cast<unsigned short*>(pb + ((32 + lr * 2 ) ^ pswz)) = f2bf(p1);
            *reinterpret_cast<unsigned short*>(pb + ((64 + lr * 2 ) ^ pswz)) = f2bf(p2);
            *reinterpret_cast<unsigned short*>(pb + ((96 + lr * 2 ) ^ pswz)) = f2bf(p3);
        }

        // ---- O += P V ----
        const char* prp = (const char*)Ps + (wq * 16 + lr) * 128;
        #pragma unroll
        for (int msd = 0; msd < 2; ++msd) {
            bf16x8 pa = *reinterpret_cast<const bf16x8*>(prp + ((msd * 64 + g * 16) ^ swz));
            #pragma unroll
            for (int cf = 0; cf < 8; ++cf) {
                const char* vrp = Vs_c + (cf * 16 + lr) * 128;
                bf16x8 vb = *reinterpret_cast<const bf16x8*>(vrp + ((msd * 64 + g * 16) ^ swz));
                acc[cf] = __builtin_amdgcn_mfma_f32_16x16x32_bf16(pa, vb, acc[cf], 0, 0, 0);
            }
        }
    }

    // ---------------- merge halves + residual + LayerNorm + transpose ----------------
    asm volatile("s_waitcnt vmcnt(0)" ::: "memory");   // dangling prefetch done
    __syncthreads();

    if (wq >= 4) {   // publish half1 partials (stride 41 floats: conflict-spread)
        float* dst = mrg + (w4 * 64 + l) * 41;
        #pragma unroll
        for (int cf = 0; cf < 8; ++cf)
            #pragma unroll
            for (int i = 0; i < 4; ++i) dst[cf * 4 + i] = acc[cf][i];
        #pragma unroll
        for (int i = 0; i < 4; ++i) { dst[32 + i] = mrun[i]; dst[36 + i] = lrun[i]; }
    }
    {   // stage x tile (c-major, stride 65) — all 512 threads
        const int c = t >> 2, h0 = (t & 3) << 4;
        const float* src = xg + (((size_t)b * CCH + c) << 12) + n0 + h0;
        float* dst = stg + c * 65 + h0;
        #pragma unroll
        for (int k = 0; k < 16; k += 4) {
            const float4 v = *reinterpret_cast<const float4*>(src + k);
            dst[k] = v.x; dst[k+1] = v.y; dst[k+2] = v.z; dst[k+3] = v.w;
        }
    }
    __syncthreads();

    if (wq < 4) {
        const float* srcm = mrg + (w4 * 64 + l) * 41;
        float g8[8], b8[8];
        #pragma unroll
        for (int cf = 0; cf < 8; ++cf) {
            g8[cf] = gamma[cf * 16 + lr];
            b8[cf] = beta[cf * 16 + lr];
        }
        #pragma unroll
        for (int i = 0; i < 4; ++i) {
            // flash combine
            const float m1 = srcm[32 + i], l1 = srcm[36 + i];
            const float mm = fmaxf(mrun[i], m1);
            const float e0 = __expf(mrun[i] - mm);
            const float e1 = __expf(m1 - mm);
            const float lm = lrun[i] * e0 + l1 * e1;
            const float inv = 1.f / lm;
            const int nloc = w4 * 16 + g * 4 + i;
            float sum = 0.f, sq = 0.f;
            #pragma unroll
            for (int cf = 0; cf < 8; ++cf) {
                const float o = acc[cf][i] * e0 + srcm[cf * 4 + i] * e1;
                const float v = o * inv + stg[(cf * 16 + lr) * 65 + nloc];
                acc[cf][i] = v; sum += v; sq += v * v;
            }
            sum += __shfl_xor(sum, 1); sq += __shfl_xor(sq, 1);
            sum += __shfl_xor(sum, 2); sq += __shfl_xor(sq, 2);
            sum += __shfl_xor(sum, 4); sq += __shfl_xor(sq, 4);
            sum += __shfl_xor(sum, 8); sq += __shfl_xor(sq, 8);
            const float mean = sum * (1.f / 128.f);
            const float var  = sq * (1.f / 128.f) - mean * mean;
            const float rstd = rsqrtf(var + 1e-5f);
            #pragma unroll
            for (int cf = 0; cf < 8; ++cf) {
                const float v = (acc[cf][i] - mean) * rstd * g8[cf] + b8[cf];
                tstg[(cf * 16 + lr) * 65 + nloc] = v;
            }
        }
    }
    __syncthreads();

    {   // coalesced transposed store — all 512 threads
        const int c = t >> 2, h0 = (t & 3) << 4;
        float* dst = out + (((size_t)b * CCH + c) << 12) + n0 + h0;
        const float* srcl = tstg + c * 65 + h0;
        #pragma unroll
        for (int k = 0; k < 16; k += 4) {
            float4 v; v.x = srcl[k]; v.y = srcl[k+1]; v.z = srcl[k+2]; v.w = srcl[k+3];
            *reinterpret_cast<float4*>(dst + k) = v;
        }
    }
}

extern "C" void kernel_launch(void* const* d_in, const int* in_sizes, int n_in,
                              void* d_out, int out_size, void* d_ws, size_t ws_size,
                              hipStream_t stream) {
    const float* prompt = (const float*)d_in[0];
    const float* x      = (const float*)d_in[1];
    const float* Wq     = (const float*)d_in[2];
    const float* bq     = (const float*)d_in[3];
    const float* Wk     = (const float*)d_in[4];
    const float* bk     = (const float*)d_in[5];
    const float* Wv     = (const float*)d_in[6];
    const float* bv     = (const float*)d_in[7];
    const float* gamma  = (const float*)d_in[8];
    const float* beta   = (const float*)d_in[9];
    const int*   maskb  = (const int*)d_in[10];
    float* out = (float*)d_out;

    const size_t M = (size_t)4 * NTOK * CCH;
    unsigned short* Qw = (unsigned short*)d_ws;
    unsigned short* Kw = Qw + M;
    unsigned short* Vw = Kw + M;

    (void)hipFuncSetAttribute((const void*)attn_ln_kernel,
                              hipFuncAttributeMaxDynamicSharedMemorySize, 147456);

    qkv_kernel<<<1024, 256, 0, stream>>>(prompt, x, Wq, bq, Wk, bk, Wv, bv, Qw, Kw, Vw);
    attn_ln_kernel<<<256, 512, 147456, stream>>>(Qw, Kw, Vw, maskb, x, gamma, beta, out);
}